// Round 1
// 238.694 us; speedup vs baseline: 1.0336x; 1.0336x over previous
//
#include <hip/hip_runtime.h>
#include <math.h>

// B=8192, T=1024, WS=5, H=6, IN=15, OUT=2
#define TLEN  1024
#define NSTEP 1019

// DPP sum over each consecutive 8-lane group (result in all 8 lanes).
template <int CTRL>
__device__ __forceinline__ float dpp_add(float v) {
    union { int i; float f; } in, out;
    in.f = v;
    out.i = __builtin_amdgcn_update_dpp(0, in.i, CTRL, 0xF, 0xF, false);
    return v + out.f;
}
__device__ __forceinline__ float sum8(float v) {
    v = dpp_add<0xB1>(v);    // quad_perm xor1
    v = dpp_add<0x4E>(v);    // quad_perm xor2
    v = dpp_add<0x141>(v);   // row_half_mirror = xor4
    return v;
}

__device__ __forceinline__ float fast_exp2(float z) {
#if __has_builtin(__builtin_amdgcn_exp2f)
    return __builtin_amdgcn_exp2f(z);
#else
    return exp2f(z);
#endif
}

__global__ __launch_bounds__(64) void MLP_or_nextstep_kernel(
    const float* __restrict__ traj,   // (B, T, 3)
    const float* __restrict__ W1,     // (6, 15)
    const float* __restrict__ b1,     // (6,)
    const float* __restrict__ W2,     // (2, 6)
    const float* __restrict__ b2,     // (2,)
    float* __restrict__ out)          // (B, 1019, 2)
{
    __shared__ float lds_u[TLEN][8];  // 32 KB: u for the block's 8 elements, all T

    const int lane = threadIdx.x;
    const int g    = lane >> 3;        // element slot (compute mapping)
    const int n    = lane & 7;         // neuron id (0..5 real; 6,7 carry biases)
    const int bstart = blockIdx.x * 8;
    const int b = bstart + g;

    const float* __restrict__ base = traj + (size_t)b * (TLEN * 3);
    float2* outb = (float2*)out + (size_t)b * NSTEP;
    const bool is_store_lane = (n == 0);

    // ---- stage ALL u rows: lane i -> elem (i&7), row 8j+(i>>3); dest word 64j+i ----
    {
        const int s_elem = lane & 7;
        const int s_row  = lane >> 3;
        const float* __restrict__ sbase = traj + (size_t)(bstart + s_elem) * (TLEN * 3);
        for (int j = 0; j < TLEN / 8; ++j) {
            const float* gp = sbase + (size_t)(8 * j + s_row) * 3;
            __builtin_amdgcn_global_load_lds(
                (const __attribute__((address_space(1))) void*)gp,
                (__attribute__((address_space(3))) void*)&lds_u[8 * j][0],
                4, 0, 0);
        }
    }

    // ---- per-lane weights, fully folded ----
    // z = (2*log2e)*preact ; tanh(preact) = 1 - 2/(2^z + 1) = 1 - 2*r
    // p = w2*tanh + bias   = fmaf(-2*w2, r, w2 + bias)
    const float KK = 2.8853900817779268f;   // 2*log2(e)
    const int nr = (n < 6) ? n : 5;
    float w1row[15], b1r;
#pragma unroll
    for (int j = 0; j < 15; ++j) w1row[j] = KK * W1[nr * 15 + j];
    b1r = KK * b1[nr];
    const float w2a_l = (n < 6) ? W2[n]     : 0.0f;
    const float w2b_l = (n < 6) ? W2[6 + n] : 0.0f;
    const float bias_a = (n == 6) ? b2[0] : 0.0f;
    const float bias_b = (n == 7) ? b2[1] : 0.0f;
    const float c1a = -2.0f * w2a_l, c0a = w2a_l + bias_a;
    const float c1b = -2.0f * w2b_l, c0b = w2b_l + bias_b;

    auto mlp = [&](const float* __restrict__ x, float& ya, float& yb) {
        float z0 = w1row[0] * x[0];
        float z1 = w1row[5] * x[5];
        float z2 = fmaf(w1row[10], x[10], b1r);
#pragma unroll
        for (int j = 1; j < 5; ++j) {
            z0 = fmaf(w1row[j],      x[j],      z0);
            z1 = fmaf(w1row[5 + j],  x[5 + j],  z1);
            z2 = fmaf(w1row[10 + j], x[10 + j], z2);
        }
        float z = (z0 + z1) + z2;
        float r = __builtin_amdgcn_rcpf(fast_exp2(z) + 1.0f);
        ya = sum8(fmaf(c1a, r, c0a));
        yb = sum8(fmaf(c1b, r, c0b));
    };

    // ---- warmup (one-time; latency-irrelevant) ----
    float uu[12], vv[5], wc[5];
#pragma unroll
    for (int i = 0; i < 12; ++i) uu[i] = base[i * 3];
#pragma unroll
    for (int i = 0; i < 5; ++i) { vv[i] = base[i * 3 + 1]; wc[i] = base[i * 3 + 2]; }

    float pa[5], pb[5];
    {
        float x[15] = {uu[0],uu[1],uu[2],uu[3],uu[4],
                       vv[0],vv[1],vv[2],vv[3],vv[4],
                       wc[0],wc[1],wc[2],wc[3],wc[4]};
        mlp(x, pa[0], pb[0]);
    }
    {
        float x[15] = {uu[1],uu[2],uu[3],uu[4],uu[5],
                       vv[1],vv[2],vv[3],vv[4],pa[0],
                       wc[1],wc[2],wc[3],wc[4],pb[0]};
        mlp(x, pa[1], pb[1]);
    }
    {
        float x[15] = {uu[2],uu[3],uu[4],uu[6],uu[7],
                       vv[2],vv[3],vv[4],pa[0],pa[1],
                       wc[2],wc[3],wc[4],pb[0],pb[1]};
        mlp(x, pa[2], pb[2]);
    }
    {
        float x[15] = {uu[3],uu[4],uu[7],uu[8],uu[9],
                       vv[3],vv[4],pa[0],pa[1],pa[2],
                       wc[3],wc[4],pb[0],pb[1],pb[2]};
        mlp(x, pa[3], pb[3]);
    }
    {
        float x[15] = {uu[4],uu[8],uu[9],uu[10],uu[11],
                       vv[4],pa[0],pa[1],pa[2],pa[3],
                       wc[4],pb[0],pb[1],pb[2],pb[3]};
        mlp(x, pa[4], pb[4]);
    }
    if (is_store_lane) {
#pragma unroll
        for (int i = 0; i < 5; ++i) outb[i] = make_float2(pa[i], pb[i]);
    }

    __syncthreads();   // staging drain, once

    // ---- scan t = 5..1018, software-pipelined ----
    float aw[5], bw[5];
#pragma unroll
    for (int i = 0; i < 5; ++i) { aw[i] = pa[i]; bw[i] = pb[i]; }

    const float* up  = &lds_u[5][g];   // group base: u[t0+i] = up[8*i]
    const float* upn;
    float2* sp = outb + n + 5;         // lane n stores step-slot n of each 8-block
    float unA[9], unB[9];

    // preload first group (t0=5) into A
#pragma unroll
    for (int i = 0; i < 9; ++i) unA[i] = up[8 * i];
    upn = up + 40;                     // next group to load: t0=10

#define LOADN(BUF)                                                           \
    {                                                                        \
        _Pragma("unroll")                                                    \
        for (int i = 0; i < 9; ++i) BUF[i] = upn[8 * i];                     \
        upn += 40;                                                           \
    }

    // du[i] = z0 chain for step i of a group (identical fma order to before)
    float duC[5], duD[5];
#pragma unroll
    for (int i = 0; i < 5; ++i) {
        float d = w1row[0] * unA[i];
        d = fmaf(w1row[1], unA[i + 1], d);
        d = fmaf(w1row[2], unA[i + 2], d);
        d = fmaf(w1row[3], unA[i + 3], d);
        d = fmaf(w1row[4], unA[i + 4], d);
        duC[i] = d;
    }

    LOADN(unB)                         // t0=10; upn -> 15

    // partials for first step (t=5, S=0): first 4 terms of z1/z2, identical order
    float pAc, pBc, pAn, pBn;
    pAc = w1row[5] * aw[0];
    pAc = fmaf(w1row[6], aw[1], pAc);
    pAc = fmaf(w1row[7], aw[2], pAc);
    pAc = fmaf(w1row[8], aw[3], pAc);
    pBc = fmaf(w1row[10], bw[0], b1r);
    pBc = fmaf(w1row[11], bw[1], pBc);
    pBc = fmaf(w1row[12], bw[2], pBc);
    pBc = fmaf(w1row[13], bw[3], pBc);

// STEP: finish step S using precomputed DUC[S]/pAc/pBc; while exp/rcp/sum8 are
// in flight, compute next step's partials and one du for the NEXT group (UN).
// All FP ops & association identical to the previous kernel.
#define STEP(S, DUC, DUN, UN, J, M)                                          \
    {                                                                        \
        float tA = fmaf(w1row[9],  aw[((S) + 4) % 5], pAc);                  \
        float tB = fmaf(w1row[14], bw[((S) + 4) % 5], pBc);                  \
        float z  = (DUC[S] + tA) + tB;                                       \
        float e  = fast_exp2(z);                                             \
        /* --- independent work placed in the exp/rcp/sum8 shadow --- */     \
        pAn = w1row[5] * aw[((S) + 1) % 5];                                  \
        pAn = fmaf(w1row[6], aw[((S) + 2) % 5], pAn);                        \
        pAn = fmaf(w1row[7], aw[((S) + 3) % 5], pAn);                        \
        pAn = fmaf(w1row[8], aw[((S) + 4) % 5], pAn);                        \
        pBn = fmaf(w1row[10], bw[((S) + 1) % 5], b1r);                       \
        pBn = fmaf(w1row[11], bw[((S) + 2) % 5], pBn);                       \
        pBn = fmaf(w1row[12], bw[((S) + 3) % 5], pBn);                       \
        pBn = fmaf(w1row[13], bw[((S) + 4) % 5], pBn);                       \
        {                                                                    \
            float d = w1row[0] * UN[S];                                      \
            d = fmaf(w1row[1], UN[(S) + 1], d);                              \
            d = fmaf(w1row[2], UN[(S) + 2], d);                              \
            d = fmaf(w1row[3], UN[(S) + 3], d);                              \
            d = fmaf(w1row[4], UN[(S) + 4], d);                              \
            DUN[S] = d;                                                      \
        }                                                                    \
        /* --- resume dependency chain --- */                                \
        float r  = __builtin_amdgcn_rcpf(e + 1.0f);                          \
        float ya = sum8(fmaf(c1a, r, c0a));                                  \
        float yb = sum8(fmaf(c1b, r, c0b));                                  \
        if (n == (J)) { ka##M = ya; kb##M = yb; }                            \
        aw[(S) % 5] = ya; bw[(S) % 5] = yb;                                  \
        pAc = pAn; pBc = pBn;                                                \
    }

#define STORE(M) sp[8 * (M)] = make_float2(ka##M, kb##M);

    // 25 superblocks x 40 steps: t = 5 .. 1004
    // gg even: compute from duC, build duD from unB, refill unA
    // gg odd : compute from duD, build duC from unA, refill unB
    for (int sb = 0; sb < 25; ++sb) {
        float ka0 = 0, kb0 = 0, ka1 = 0, kb1 = 0, ka2 = 0, kb2 = 0,
              ka3 = 0, kb3 = 0, ka4 = 0, kb4 = 0;
        // gg0
        LOADN(unA)
        STEP(0, duC, duD, unB, 0, 0) STEP(1, duC, duD, unB, 1, 0) STEP(2, duC, duD, unB, 2, 0)
        STEP(3, duC, duD, unB, 3, 0) STEP(4, duC, duD, unB, 4, 0)
        // gg1
        LOADN(unB)
        STEP(0, duD, duC, unA, 5, 0) STEP(1, duD, duC, unA, 6, 0) STEP(2, duD, duC, unA, 7, 0) STORE(0)
        STEP(3, duD, duC, unA, 0, 1) STEP(4, duD, duC, unA, 1, 1)
        // gg2
        LOADN(unA)
        STEP(0, duC, duD, unB, 2, 1) STEP(1, duC, duD, unB, 3, 1) STEP(2, duC, duD, unB, 4, 1)
        STEP(3, duC, duD, unB, 5, 1) STEP(4, duC, duD, unB, 6, 1)
        // gg3
        LOADN(unB)
        STEP(0, duD, duC, unA, 7, 1) STORE(1)
        STEP(1, duD, duC, unA, 0, 2) STEP(2, duD, duC, unA, 1, 2) STEP(3, duD, duC, unA, 2, 2) STEP(4, duD, duC, unA, 3, 2)
        // gg4
        LOADN(unA)
        STEP(0, duC, duD, unB, 4, 2) STEP(1, duC, duD, unB, 5, 2) STEP(2, duC, duD, unB, 6, 2)
        STEP(3, duC, duD, unB, 7, 2) STORE(2)
        STEP(4, duC, duD, unB, 0, 3)
        // gg5
        LOADN(unB)
        STEP(0, duD, duC, unA, 1, 3) STEP(1, duD, duC, unA, 2, 3) STEP(2, duD, duC, unA, 3, 3)
        STEP(3, duD, duC, unA, 4, 3) STEP(4, duD, duC, unA, 5, 3)
        // gg6
        LOADN(unA)
        STEP(0, duC, duD, unB, 6, 3) STEP(1, duC, duD, unB, 7, 3) STORE(3)
        STEP(2, duC, duD, unB, 0, 4) STEP(3, duC, duD, unB, 1, 4) STEP(4, duC, duD, unB, 2, 4)
        // gg7
        LOADN(unB)
        STEP(0, duD, duC, unA, 3, 4) STEP(1, duD, duC, unA, 4, 4) STEP(2, duD, duC, unA, 5, 4)
        STEP(3, duD, duC, unA, 6, 4) STEP(4, duD, duC, unA, 7, 4) STORE(4)

        sp += 40;
    }

    // ---- tail: t = 1005..1018 (14 steps), per-step lane-0 stores ----
    // state: unA holds rows 1005..1013, unB holds 1010..1018, upn -> 1015
    float2* tp = outb + 1005;
#define TSTEP(S, UN, K)                                                      \
    {                                                                        \
        float z0 = w1row[0] * UN[S];                                         \
        float z1 = w1row[5] * aw[(S) % 5];                                   \
        float z2 = fmaf(w1row[10], bw[(S) % 5], b1r);                        \
        z0 = fmaf(w1row[1], UN[(S) + 1], z0);                                \
        z1 = fmaf(w1row[6], aw[((S) + 1) % 5], z1);                          \
        z2 = fmaf(w1row[11], bw[((S) + 1) % 5], z2);                         \
        z0 = fmaf(w1row[2], UN[(S) + 2], z0);                                \
        z1 = fmaf(w1row[7], aw[((S) + 2) % 5], z1);                          \
        z2 = fmaf(w1row[12], bw[((S) + 2) % 5], z2);                         \
        z0 = fmaf(w1row[3], UN[(S) + 3], z0);                                \
        z1 = fmaf(w1row[8], aw[((S) + 3) % 5], z1);                          \
        z2 = fmaf(w1row[13], bw[((S) + 3) % 5], z2);                         \
        z0 = fmaf(w1row[4], UN[(S) + 4], z0);                                \
        z1 = fmaf(w1row[9], aw[((S) + 4) % 5], z1);                          \
        z2 = fmaf(w1row[14], bw[((S) + 4) % 5], z2);                         \
        float z = (z0 + z1) + z2;                                            \
        float r = __builtin_amdgcn_rcpf(fast_exp2(z) + 1.0f);                \
        float ya = sum8(fmaf(c1a, r, c0a));                                  \
        float yb = sum8(fmaf(c1b, r, c0b));                                  \
        if (is_store_lane) tp[K] = make_float2(ya, yb);                      \
        aw[(S) % 5] = ya; bw[(S) % 5] = yb;                                  \
    }

    TSTEP(0, unA, 0) TSTEP(1, unA, 1) TSTEP(2, unA, 2) TSTEP(3, unA, 3) TSTEP(4, unA, 4)
    LOADN(unA)   // t0=1015, rows 1015..1023 (in bounds)
    TSTEP(0, unB, 5) TSTEP(1, unB, 6) TSTEP(2, unB, 7) TSTEP(3, unB, 8) TSTEP(4, unB, 9)
    TSTEP(0, unA, 10) TSTEP(1, unA, 11) TSTEP(2, unA, 12) TSTEP(3, unA, 13)

#undef TSTEP
#undef STORE
#undef STEP
#undef LOADN
}

extern "C" void kernel_launch(void* const* d_in, const int* in_sizes, int n_in,
                              void* d_out, int out_size, void* d_ws, size_t ws_size,
                              hipStream_t stream) {
    const float* traj = (const float*)d_in[0];
    const float* W1   = (const float*)d_in[1];
    const float* b1   = (const float*)d_in[2];
    const float* W2   = (const float*)d_in[3];
    const float* b2   = (const float*)d_in[4];
    float* out = (float*)d_out;

    // 8 lanes/element, 8 elements/wave -> 1024 single-wave blocks = 1 wave/SIMD chip-wide
    const int grid = 8192 / 8;
    MLP_or_nextstep_kernel<<<grid, 64, 0, stream>>>(traj, W1, b1, W2, b2, out);
}